// Round 5
// baseline (240.317 us; speedup 1.0000x reference)
//
#include <hip/hip_runtime.h>

// out[row] = sum_edges(0.4*val * x[col]) - x[row] + e[row]
// Strategy: one-pass padded-bucket binning (atomic cursor per row, CAP=40,
// 320B line-aligned bucket stride), then atomic-free per-row gather using
// branch-free predicated 8-deep load bursts (max MLP, no serial tail) with
// fused epilogue. Bucket overflow (effectively impossible for Poisson(6.25)
// degrees, but handled for safety) is repaired by a tiny atomic kernel.

#define EMB_DIM 128
#define Q_SLOTS 32            // EMB_DIM/4 float4 slots per row
#define CAP 40                // bucket capacity; 40*8B = 320B = 5 cache lines
#define OVF_MAX 4096
#define BURST 8               // predicated load burst depth

// ---- Build: slots[r*CAP + pos] = {col, 0.4*val} ----
__global__ void build_buckets_kernel(const int* __restrict__ rows,
                                     const int* __restrict__ cols,
                                     const float* __restrict__ vals,
                                     int* __restrict__ counts,
                                     int2* __restrict__ slots,
                                     int* __restrict__ ovf_cursor,
                                     int4* __restrict__ ovf,
                                     int n_edges) {
    int i = blockIdx.x * blockDim.x + threadIdx.x;
    if (i >= n_edges) return;
    int r = rows[i];
    int2 p;
    p.x = cols[i];
    p.y = __float_as_int(0.4f * vals[i]);
    int pos = atomicAdd(&counts[r], 1);
    if (pos < CAP) {
        slots[(size_t)r * CAP + pos] = p;
    } else {
        int o = atomicAdd(ovf_cursor, 1);
        if (o < OVF_MAX) ovf[o] = make_int4(r, p.x, p.y, 0);
    }
}

// ---- Gather: 32 lanes/row; predicated 8-deep bursts; fused epilogue ----
__global__ void gather_buckets_kernel(const float4* __restrict__ x4,
                                      const float4* __restrict__ e4,
                                      const int* __restrict__ counts,
                                      const int2* __restrict__ slots,
                                      float4* __restrict__ out4, int n_nodes) {
    int tid = blockIdx.x * blockDim.x + threadIdx.x;
    int row = tid >> 5;
    int q   = tid & 31;
    if (row >= n_nodes) return;

    int n = counts[row];
    n = (n < CAP) ? n : CAP;
    const int2* b = slots + (size_t)row * CAP;

    float4 acc = make_float4(0.f, 0.f, 0.f, 0.f);

    for (int base = 0; base < n; base += BURST) {
        int m = n - base;                 // edges remaining (>=1)
        // Issue all payload loads (indices clamped to valid slots — never
        // touch uninitialized/poisoned slots).
        int2 p[BURST];
#pragma unroll
        for (int k = 0; k < BURST; ++k) {
            int jj = base + ((k < m) ? k : 0);
            p[k] = b[jj];
        }
        // Issue all x-row loads (duplicates for k>=m hit the same line).
        float4 xv[BURST];
#pragma unroll
        for (int k = 0; k < BURST; ++k) {
            xv[k] = x4[p[k].x * Q_SLOTS + q];
        }
        // Predicated accumulate.
#pragma unroll
        for (int k = 0; k < BURST; ++k) {
            float v = (k < m) ? __int_as_float(p[k].y) : 0.f;
            acc.x = fmaf(v, xv[k].x, acc.x);
            acc.y = fmaf(v, xv[k].y, acc.y);
            acc.z = fmaf(v, xv[k].z, acc.z);
            acc.w = fmaf(v, xv[k].w, acc.w);
        }
    }

    int idx = row * Q_SLOTS + q;
    float4 xr = x4[idx];
    float4 er = e4[idx];
    out4[idx] = make_float4(acc.x + er.x - xr.x,
                            acc.y + er.y - xr.y,
                            acc.z + er.z - xr.z,
                            acc.w + er.w - xr.w);
}

// ---- Overflow repair: 32 lanes per overflow entry, runs after gather ----
__global__ void ovf_fix_kernel(const int* __restrict__ ovf_cursor,
                               const int4* __restrict__ ovf,
                               const float* __restrict__ x,
                               float* __restrict__ out) {
    int tid = blockIdx.x * blockDim.x + threadIdx.x;
    int k = tid >> 5;
    int q = tid & 31;
    int cnt = *ovf_cursor;
    cnt = (cnt < OVF_MAX) ? cnt : OVF_MAX;
    if (k >= cnt) return;
    int4 en = ovf[k];
    float v = __int_as_float(en.z);
    float4 m = ((const float4*)(x + (size_t)en.y * EMB_DIM))[q];
    float* o = out + (size_t)en.x * EMB_DIM + q * 4;
    atomicAdd(o + 0, v * m.x);
    atomicAdd(o + 1, v * m.y);
    atomicAdd(o + 2, v * m.z);
    atomicAdd(o + 3, v * m.w);
}

// ---- Fallback (ws too small): chain approach from round 3 ----
__global__ void build_chain_kernel(const int* __restrict__ rows,
                                   const int* __restrict__ cols,
                                   const float* __restrict__ vals,
                                   int* __restrict__ head,
                                   int4* __restrict__ nodes, int n_edges) {
    int i = blockIdx.x * blockDim.x + threadIdx.x;
    if (i >= n_edges) return;
    int r = rows[i];
    int prev = atomicExch(&head[r], i);
    nodes[i] = make_int4(cols[i], __float_as_int(0.4f * vals[i]), prev, 0);
}
__global__ void gather_chain_kernel(const float2* __restrict__ x2,
                                    const float2* __restrict__ e2,
                                    const int* __restrict__ head,
                                    const int4* __restrict__ nodes,
                                    float2* __restrict__ out2, int n_nodes) {
    int tid = blockIdx.x * blockDim.x + threadIdx.x;
    int row = tid >> 6, q = tid & 63;
    if (row >= n_nodes) return;
    float2 acc = make_float2(0.f, 0.f);
    int j = head[row];
    if (j >= 0) {
        int4 nd = nodes[j];
        for (;;) {
            int4 nd2;
            bool more = (nd.z >= 0);
            if (more) nd2 = nodes[nd.z];
            float v = __int_as_float(nd.y);
            float2 xv = x2[nd.x * 64 + q];
            acc.x = fmaf(v, xv.x, acc.x);
            acc.y = fmaf(v, xv.y, acc.y);
            if (!more) break;
            nd = nd2;
        }
    }
    int idx = row * 64 + q;
    float2 xr = x2[idx], er = e2[idx];
    out2[idx] = make_float2(acc.x + er.x - xr.x, acc.y + er.y - xr.y);
}

extern "C" void kernel_launch(void* const* d_in, const int* in_sizes, int n_in,
                              void* d_out, int out_size, void* d_ws, size_t ws_size,
                              hipStream_t stream) {
    // Inputs: t, x, e, hg_vals, hg_rows, hg_cols
    const float* x    = (const float*)d_in[1];
    const float* e    = (const float*)d_in[2];
    const float* vals = (const float*)d_in[3];
    const int*   rows = (const int*)d_in[4];
    const int*   cols = (const int*)d_in[5];
    float* out = (float*)d_out;

    const int n_edges = in_sizes[3];
    const int n_nodes = in_sizes[1] / EMB_DIM;

    // Workspace layout: ovf list (16B aligned), slots, counts, ovf_cursor
    size_t need = (size_t)OVF_MAX * sizeof(int4) +
                  (size_t)n_nodes * CAP * sizeof(int2) +
                  (size_t)(n_nodes + 1) * sizeof(int);

    if (ws_size >= need) {
        int4* ovf        = (int4*)d_ws;
        int2* slots      = (int2*)(ovf + OVF_MAX);
        int*  counts     = (int*)(slots + (size_t)n_nodes * CAP);
        int*  ovf_cursor = counts + n_nodes;

        // zero counts + cursor in one memset (adjacent)
        hipMemsetAsync(counts, 0, (size_t)(n_nodes + 1) * sizeof(int), stream);

        int eb = (n_edges + 255) / 256;
        build_buckets_kernel<<<eb, 256, 0, stream>>>(rows, cols, vals, counts,
                                                     slots, ovf_cursor, ovf,
                                                     n_edges);

        long long gt = (long long)n_nodes * 32;
        int gb = (int)((gt + 255) / 256);
        gather_buckets_kernel<<<gb, 256, 0, stream>>>((const float4*)x,
                                                      (const float4*)e,
                                                      counts, slots,
                                                      (float4*)out, n_nodes);

        int ob = (OVF_MAX * 32 + 255) / 256;
        ovf_fix_kernel<<<ob, 256, 0, stream>>>(ovf_cursor, ovf, x, out);
    } else {
        // Fallback: chain approach (round 3)
        int4* nodes = (int4*)d_ws;
        int*  head  = (int*)(nodes + n_edges);
        hipMemsetAsync(head, 0xFF, (size_t)n_nodes * sizeof(int), stream);
        int eb = (n_edges + 255) / 256;
        build_chain_kernel<<<eb, 256, 0, stream>>>(rows, cols, vals, head,
                                                   nodes, n_edges);
        long long gt = (long long)n_nodes * 64;
        int gb = (int)((gt + 255) / 256);
        gather_chain_kernel<<<gb, 256, 0, stream>>>((const float2*)x,
                                                    (const float2*)e,
                                                    head, nodes,
                                                    (float2*)out, n_nodes);
    }
}

// Round 6
// 232.294 us; speedup vs baseline: 1.0345x; 1.0345x over previous
//
#include <hip/hip_runtime.h>

// out[row] = sum_edges(0.4*val * x[col]) - x[row] + e[row]
// Strategy: one-pass padded-bucket binning (atomic cursor per row, CAP=40),
// then atomic-free gather: 32 lanes/row load ALL payloads in ONE coalesced
// instruction (lane q holds payload q), broadcast each edge via __shfl, and
// issue all x-row loads back-to-back (MLP = row degree). Fused epilogue.
// Bucket overflow repaired by a tiny atomic kernel (prob ~0 for Poisson(6.25)).

#define EMB_DIM 128
#define Q_SLOTS 32            // EMB_DIM/4 float4 slots per row
#define CAP 40                // bucket capacity; 40*8B = 320B bucket stride
#define OVF_MAX 4096

// ---- Build: slots[r*CAP + pos] = {col, 0.4*val} ----
__global__ void build_buckets_kernel(const int* __restrict__ rows,
                                     const int* __restrict__ cols,
                                     const float* __restrict__ vals,
                                     int* __restrict__ counts,
                                     int2* __restrict__ slots,
                                     int* __restrict__ ovf_cursor,
                                     int4* __restrict__ ovf,
                                     int n_edges) {
    int i = blockIdx.x * blockDim.x + threadIdx.x;
    if (i >= n_edges) return;
    int r = rows[i];
    int2 p;
    p.x = cols[i];
    p.y = __float_as_int(0.4f * vals[i]);
    int pos = atomicAdd(&counts[r], 1);
    if (pos < CAP) {
        slots[(size_t)r * CAP + pos] = p;
    } else {
        int o = atomicAdd(ovf_cursor, 1);
        if (o < OVF_MAX) ovf[o] = make_int4(r, p.x, p.y, 0);
    }
}

// ---- Gather: 32 lanes/row; 1 payload load + shfl broadcast; fused epilogue ----
__global__ void gather_buckets_kernel(const float4* __restrict__ x4,
                                      const float4* __restrict__ e4,
                                      const int* __restrict__ counts,
                                      const int2* __restrict__ slots,
                                      float4* __restrict__ out4, int n_nodes) {
    int tid = blockIdx.x * blockDim.x + threadIdx.x;
    int row = tid >> 5;
    int q   = tid & 31;
    if (row >= n_nodes) return;

    int n = counts[row];
    n = (n < CAP) ? n : CAP;
    const int2* b = slots + (size_t)row * CAP;

    // One coalesced load covers the first 32 payloads: lane q holds b[q].
    // (q < 32 <= CAP so always in-bounds; unused lanes may hold poison —
    //  never dereferenced because jc clamps to n-1 below.)
    int2 myp = b[q];

    float4 acc = make_float4(0.f, 0.f, 0.f, 0.f);
    int nm1 = n - 1;

    // Groups of 8; all addresses come from shfl (registers), so the 8 x-loads
    // issue back-to-back. Clamped k>=n duplicates hit the j=n-1 line (L1 hit)
    // and contribute v=0.
    for (int base = 0; base < n && base < 32; base += 8) {
        int   col[8];
        float v[8];
#pragma unroll
        for (int k = 0; k < 8; ++k) {
            int j  = base + k;
            int jc = (j < n) ? j : nm1;
            col[k] = __shfl(myp.x, jc, 32);
            int vi = __shfl(myp.y, jc, 32);
            v[k]   = (j < n) ? __int_as_float(vi) : 0.f;
        }
        float4 xv[8];
#pragma unroll
        for (int k = 0; k < 8; ++k) {
            xv[k] = x4[col[k] * Q_SLOTS + q];
        }
#pragma unroll
        for (int k = 0; k < 8; ++k) {
            acc.x = fmaf(v[k], xv[k].x, acc.x);
            acc.y = fmaf(v[k], xv[k].y, acc.y);
            acc.z = fmaf(v[k], xv[k].z, acc.z);
            acc.w = fmaf(v[k], xv[k].w, acc.w);
        }
    }
    // Rare residual (n > 32): serial, correctness only.
    for (int j = 32; j < n; ++j) {
        int2 p = b[j];
        float vv = __int_as_float(p.y);
        float4 m = x4[p.x * Q_SLOTS + q];
        acc.x = fmaf(vv, m.x, acc.x);
        acc.y = fmaf(vv, m.y, acc.y);
        acc.z = fmaf(vv, m.z, acc.z);
        acc.w = fmaf(vv, m.w, acc.w);
    }

    int idx = row * Q_SLOTS + q;
    float4 xr = x4[idx];
    float4 er = e4[idx];
    out4[idx] = make_float4(acc.x + er.x - xr.x,
                            acc.y + er.y - xr.y,
                            acc.z + er.z - xr.z,
                            acc.w + er.w - xr.w);
}

// ---- Overflow repair: 32 lanes per overflow entry, runs after gather ----
__global__ void ovf_fix_kernel(const int* __restrict__ ovf_cursor,
                               const int4* __restrict__ ovf,
                               const float* __restrict__ x,
                               float* __restrict__ out) {
    int tid = blockIdx.x * blockDim.x + threadIdx.x;
    int k = tid >> 5;
    int q = tid & 31;
    int cnt = *ovf_cursor;
    cnt = (cnt < OVF_MAX) ? cnt : OVF_MAX;
    if (k >= cnt) return;
    int4 en = ovf[k];
    float v = __int_as_float(en.z);
    float4 m = ((const float4*)(x + (size_t)en.y * EMB_DIM))[q];
    float* o = out + (size_t)en.x * EMB_DIM + q * 4;
    atomicAdd(o + 0, v * m.x);
    atomicAdd(o + 1, v * m.y);
    atomicAdd(o + 2, v * m.z);
    atomicAdd(o + 3, v * m.w);
}

// ---- Fallback (ws too small): chain approach from round 3 ----
__global__ void build_chain_kernel(const int* __restrict__ rows,
                                   const int* __restrict__ cols,
                                   const float* __restrict__ vals,
                                   int* __restrict__ head,
                                   int4* __restrict__ nodes, int n_edges) {
    int i = blockIdx.x * blockDim.x + threadIdx.x;
    if (i >= n_edges) return;
    int r = rows[i];
    int prev = atomicExch(&head[r], i);
    nodes[i] = make_int4(cols[i], __float_as_int(0.4f * vals[i]), prev, 0);
}
__global__ void gather_chain_kernel(const float2* __restrict__ x2,
                                    const float2* __restrict__ e2,
                                    const int* __restrict__ head,
                                    const int4* __restrict__ nodes,
                                    float2* __restrict__ out2, int n_nodes) {
    int tid = blockIdx.x * blockDim.x + threadIdx.x;
    int row = tid >> 6, q = tid & 63;
    if (row >= n_nodes) return;
    float2 acc = make_float2(0.f, 0.f);
    int j = head[row];
    if (j >= 0) {
        int4 nd = nodes[j];
        for (;;) {
            int4 nd2;
            bool more = (nd.z >= 0);
            if (more) nd2 = nodes[nd.z];
            float v = __int_as_float(nd.y);
            float2 xv = x2[nd.x * 64 + q];
            acc.x = fmaf(v, xv.x, acc.x);
            acc.y = fmaf(v, xv.y, acc.y);
            if (!more) break;
            nd = nd2;
        }
    }
    int idx = row * 64 + q;
    float2 xr = x2[idx], er = e2[idx];
    out2[idx] = make_float2(acc.x + er.x - xr.x, acc.y + er.y - xr.y);
}

extern "C" void kernel_launch(void* const* d_in, const int* in_sizes, int n_in,
                              void* d_out, int out_size, void* d_ws, size_t ws_size,
                              hipStream_t stream) {
    // Inputs: t, x, e, hg_vals, hg_rows, hg_cols
    const float* x    = (const float*)d_in[1];
    const float* e    = (const float*)d_in[2];
    const float* vals = (const float*)d_in[3];
    const int*   rows = (const int*)d_in[4];
    const int*   cols = (const int*)d_in[5];
    float* out = (float*)d_out;

    const int n_edges = in_sizes[3];
    const int n_nodes = in_sizes[1] / EMB_DIM;

    // Workspace layout: ovf list (16B aligned), slots, counts, ovf_cursor
    size_t need = (size_t)OVF_MAX * sizeof(int4) +
                  (size_t)n_nodes * CAP * sizeof(int2) +
                  (size_t)(n_nodes + 1) * sizeof(int);

    if (ws_size >= need) {
        int4* ovf        = (int4*)d_ws;
        int2* slots      = (int2*)(ovf + OVF_MAX);
        int*  counts     = (int*)(slots + (size_t)n_nodes * CAP);
        int*  ovf_cursor = counts + n_nodes;

        // zero counts + cursor in one memset (adjacent)
        hipMemsetAsync(counts, 0, (size_t)(n_nodes + 1) * sizeof(int), stream);

        int eb = (n_edges + 255) / 256;
        build_buckets_kernel<<<eb, 256, 0, stream>>>(rows, cols, vals, counts,
                                                     slots, ovf_cursor, ovf,
                                                     n_edges);

        long long gt = (long long)n_nodes * 32;
        int gb = (int)((gt + 255) / 256);
        gather_buckets_kernel<<<gb, 256, 0, stream>>>((const float4*)x,
                                                      (const float4*)e,
                                                      counts, slots,
                                                      (float4*)out, n_nodes);

        int ob = (OVF_MAX * 32 + 255) / 256;
        ovf_fix_kernel<<<ob, 256, 0, stream>>>(ovf_cursor, ovf, x, out);
    } else {
        // Fallback: chain approach (round 3)
        int4* nodes = (int4*)d_ws;
        int*  head  = (int*)(nodes + n_edges);
        hipMemsetAsync(head, 0xFF, (size_t)n_nodes * sizeof(int), stream);
        int eb = (n_edges + 255) / 256;
        build_chain_kernel<<<eb, 256, 0, stream>>>(rows, cols, vals, head,
                                                   nodes, n_edges);
        long long gt = (long long)n_nodes * 64;
        int gb = (int)((gt + 255) / 256);
        gather_chain_kernel<<<gb, 256, 0, stream>>>((const float2*)x,
                                                    (const float2*)e,
                                                    head, nodes,
                                                    (float2*)out, n_nodes);
    }
}